// Round 2
// baseline (256.208 us; speedup 1.0000x reference)
//
#include <hip/hip_runtime.h>
#include <hip/hip_bf16.h>

// ---------------- problem constants ----------------
#define NTOK   8192
#define TOPK   2
#define NROWS  (NTOK*TOPK)      // 16384
#define NEXP   8
#define KDIM   1024             // inner (INTER)
#define NDIM   2048             // output (HIDDEN)
#define MAX_TILES 136           // sum of ceil(cnt_e/128) <= 128+8 (grid uses 136)
#define NTILE  (NDIM/128)       // 16
#define GRID_G (MAX_TILES*NTILE) // 2176, divisible by 8

typedef __bf16 bf16_t;
typedef __bf16 bf16x8 __attribute__((ext_vector_type(8)));
typedef __bf16 bf16x4 __attribute__((ext_vector_type(4)));
typedef float  f32x4  __attribute__((ext_vector_type(4)));

static_assert(sizeof(bf16x8) == 16, "bf16x8 must be 16B");

// ---------------- ws layout (bytes) ----------------
#define OFF_TW    ((size_t)0)                    // 16384 f32 = 64KB
#define OFF_CNT   ((size_t)(1<<16))              // 8 i32
#define OFF_WL    ((size_t)((1<<16) + 1024))     // 136 * int4
#define OFF_RL    ((size_t)(1<<18))              // 8*16384 i32 = 512KB
#define OFF_XB    ((size_t)(1<<20))              // 16384*1024 bf16 = 32MB
#define OFF_WB    ((size_t)(34u<<20))            // 8*2048*1024 bf16 = 32MB
#define OFF_SCR   ((size_t)(68u<<20))            // scratch
#define NEED_F32  (OFF_SCR + (size_t)NROWS*NDIM*4)   // ~196MB
#define NEED_BF16 (OFF_SCR + (size_t)NROWS*NDIM*2)   // ~132MB

__device__ __forceinline__ void gload_lds16(const void* g, void* l) {
  __builtin_amdgcn_global_load_lds(
      (const __attribute__((address_space(1))) void*)g,
      (__attribute__((address_space(3))) void*)l, 16, 0, 0);
}

// ---------------- 1. routing: softmax + top2 + bucket (fused) ----------------
__global__ void routing_kernel(const float* __restrict__ logits,
                               float* __restrict__ tw,
                               int* __restrict__ cnt, int* __restrict__ rowlist) {
  int t = blockIdx.x * blockDim.x + threadIdx.x;
  if (t >= NTOK) return;
  float4 a = *(const float4*)(logits + (size_t)t*NEXP);
  float4 b = *(const float4*)(logits + (size_t)t*NEXP + 4);
  float l[8] = {a.x, a.y, a.z, a.w, b.x, b.y, b.z, b.w};
  float m = l[0];
#pragma unroll
  for (int i = 1; i < 8; i++) m = fmaxf(m, l[i]);
  float p[8], s = 0.f;
#pragma unroll
  for (int i = 0; i < 8; i++) { p[i] = __expf(l[i] - m); s += p[i]; }
  // top-1 (lowest index on ties -> strict >)
  int e0 = 0; float b0 = p[0];
#pragma unroll
  for (int i = 1; i < 8; i++) if (p[i] > b0) { b0 = p[i]; e0 = i; }
  int e1 = (e0 == 0) ? 1 : 0; float b1 = p[e1];
#pragma unroll
  for (int i = 0; i < 8; i++) if (i != e0 && p[i] > b1) { b1 = p[i]; e1 = i; }
  float inv = 1.f / s;
  tw[2*t]   = b0 * inv;
  tw[2*t+1] = b1 * inv;
  int pos0 = atomicAdd(&cnt[e0], 1);
  rowlist[(size_t)e0*NROWS + pos0] = 2*t;
  int pos1 = atomicAdd(&cnt[e1], 1);
  rowlist[(size_t)e1*NROWS + pos1] = 2*t + 1;
}

// ---------------- 2. worklist of (expert,row-tile), parallel ----------------
__global__ void build_wl_kernel(const int* __restrict__ cnt, int4* __restrict__ wl) {
  __shared__ int base[NEXP+1];
  if (threadIdx.x == 0) {
    int acc = 0;
    for (int e = 0; e < NEXP; e++) { base[e] = acc; acc += (cnt[e] + 127) >> 7; }
    base[NEXP] = acc;
  }
  __syncthreads();
  int t = threadIdx.x;
  if (t < MAX_TILES) {
    int4 v = {0, 0, 0, 0};
#pragma unroll
    for (int e = 0; e < NEXP; e++) {
      if (t >= base[e] && t < base[e+1]) {
        int rb = (t - base[e]) << 7;
        int c  = cnt[e];
        v.x = e; v.y = rb; v.z = (c - rb < 128) ? (c - rb) : 128;
      }
    }
    wl[t] = v;
  }
}

// ---------------- 3a. convert x -> bf16 (bf16x8 stores) ----------------
__global__ void cvt_x_kernel(const float* __restrict__ x, bf16_t* __restrict__ xb) {
  const int n8 = NROWS * KDIM / 8;
  int stride = gridDim.x * blockDim.x;
  for (int i = blockIdx.x * blockDim.x + threadIdx.x; i < n8; i += stride) {
    float4 v0 = ((const float4*)x)[2*(size_t)i];
    float4 v1 = ((const float4*)x)[2*(size_t)i + 1];
    bf16x8 o = { (bf16_t)v0.x, (bf16_t)v0.y, (bf16_t)v0.z, (bf16_t)v0.w,
                 (bf16_t)v1.x, (bf16_t)v1.y, (bf16_t)v1.z, (bf16_t)v1.w };
    *(bf16x8*)(xb + (size_t)i*8) = o;
  }
}

// ---------------- 3b. convert+transpose w -> bf16 [E][N][K] ----------------
// 64n x 64k tile per block, 16B coalesced reads and writes.
__global__ void cvt_w_kernel(const float* __restrict__ w, bf16_t* __restrict__ wb) {
  __shared__ bf16_t tile[64][72];   // [n][k], row stride 144B (16B-aligned)
  int e  = blockIdx.z;
  int n0 = blockIdx.x * 64;
  int k0 = blockIdx.y * 64;
  int t  = threadIdx.x;
  const float* srcbase = w + (size_t)e * KDIM * NDIM + (size_t)k0 * NDIM + n0;
#pragma unroll
  for (int i = 0; i < 4; i++) {
    int idx = t + i*256;          // 0..1023
    int kr  = idx >> 4;           // 0..63
    int nc4 = (idx & 15) * 4;     // 0..60
    float4 v = *(const float4*)(srcbase + (size_t)kr * NDIM + nc4);
    tile[nc4+0][kr] = (bf16_t)v.x;
    tile[nc4+1][kr] = (bf16_t)v.y;
    tile[nc4+2][kr] = (bf16_t)v.z;
    tile[nc4+3][kr] = (bf16_t)v.w;
  }
  __syncthreads();
  bf16_t* dstbase = wb + (size_t)e * NDIM * KDIM + (size_t)n0 * KDIM + k0;
#pragma unroll
  for (int i = 0; i < 2; i++) {
    int idx = t + i*256;          // 0..511
    int nr  = idx >> 3;           // 0..63
    int kc  = (idx & 7) * 8;      // 0..56
    bf16x8 o = *(const bf16x8*)&tile[nr][kc];
    *(bf16x8*)(dstbase + (size_t)nr * KDIM + kc) = o;
  }
}

// ---------------- 4. grouped GEMM (m97 structure + LDS swizzle + XCD swizzle) ----
// tile 128x128, BK=32, 4 waves (each 64x64), mfma_f32_16x16x32_bf16
// LDS tile [row][32] bf16, but 16B slots within a row permuted: slot' = slot ^ ((row>>1)&3)
// MODE 0: fp32 scratch   MODE 1: bf16 scratch   MODE 2: atomic into out
template <int MODE>
__global__ __launch_bounds__(256)
void gemm_kernel(const bf16_t* __restrict__ xb,     // [NROWS][KDIM]
                 const bf16_t* __restrict__ wb,     // [NEXP][NDIM][KDIM]
                 const int*    __restrict__ rowlist,
                 const int4*   __restrict__ wl,
                 const float*  __restrict__ tw,
                 float*        __restrict__ scrf,
                 bf16_t*       __restrict__ scrb,
                 float*        __restrict__ outp) {
  __shared__ bf16_t As[128 * 32];   // [row][k-slot swizzled]
  __shared__ bf16_t Bs[128 * 32];   // [n][k-slot swizzled]

  // XCD-bijective swizzle: 2176 blocks, 8 XCDs, 272 per XCD, x(n-tile) fastest
  int bid = blockIdx.x;
  int lin = (bid & 7) * (GRID_G/8) + (bid >> 3);
  int xt  = lin & (NTILE-1);
  int yt  = lin / NTILE;

  int4 wle = wl[yt];
  const int nrows = wle.z;
  if (nrows <= 0) return;
  const int e  = wle.x;
  const int n0 = xt * 128;

  const int t    = threadIdx.x;
  const int lane = t & 63;
  const int wv   = t >> 6;

  // staging: thread t owns LDS rows t/4 (i=0) and 64+t/4 (i=1)
  // linear LDS dest -> load the INVERSE-swizzled global k-slot
  const int arow  = t >> 2;
  const int kslot = (((t & 3) ^ ((arow >> 1) & 3)) * 8);
  const int* rl = rowlist + (size_t)e * NROWS + wle.y;
  int r0 = rl[(arow      < nrows) ? arow      : (nrows - 1)];
  int r1 = rl[(64 + arow < nrows) ? 64 + arow : (nrows - 1)];

  const bf16_t* gA0 = xb + (size_t)r0 * KDIM + kslot;
  const bf16_t* gA1 = xb + (size_t)r1 * KDIM + kslot;
  const bf16_t* gB0 = wb + (size_t)e * NDIM * KDIM + (size_t)(n0 + arow) * KDIM + kslot;
  const bf16_t* gB1 = gB0 + (size_t)64 * KDIM;

  bf16_t* ldsA0 = &As[(0*256 + wv*64) * 8];
  bf16_t* ldsA1 = &As[(1*256 + wv*64) * 8];
  bf16_t* ldsB0 = &Bs[(0*256 + wv*64) * 8];
  bf16_t* ldsB1 = &Bs[(1*256 + wv*64) * 8];

  f32x4 acc[4][4] = {};

  const int wr  = (wv >> 1) * 64;   // wave row offset in tile
  const int wc  = (wv & 1) * 64;    // wave col offset in tile
  const int lr  = lane & 15;
  const int lslot = lane >> 4;      // 16B k-slot index 0..3

  for (int k0 = 0; k0 < KDIM; k0 += 32) {
    __syncthreads();                 // previous reads done before overwrite
    gload_lds16(gA0, ldsA0);
    gload_lds16(gA1, ldsA1);
    gload_lds16(gB0, ldsB0);
    gload_lds16(gB1, ldsB1);
    gA0 += 32; gA1 += 32; gB0 += 32; gB1 += 32;
    __syncthreads();                 // drains vmcnt before use

    bf16x8 af[4], bfr[4];
#pragma unroll
    for (int mi = 0; mi < 4; mi++) {
      int rrow = wr + mi*16 + lr;
      af[mi] = *(const bf16x8*)&As[rrow*32 + ((lslot ^ ((rrow >> 1) & 3)) << 3)];
    }
#pragma unroll
    for (int ni = 0; ni < 4; ni++) {
      int rrow = wc + ni*16 + lr;
      bfr[ni] = *(const bf16x8*)&Bs[rrow*32 + ((lslot ^ ((rrow >> 1) & 3)) << 3)];
    }
#pragma unroll
    for (int mi = 0; mi < 4; mi++)
#pragma unroll
      for (int ni = 0; ni < 4; ni++)
        acc[mi][ni] = __builtin_amdgcn_mfma_f32_16x16x32_bf16(af[mi], bfr[ni], acc[mi][ni], 0, 0, 0);
  }

  // epilogue: C/D layout col = lane&15, row = (lane>>4)*4 + j
#pragma unroll
  for (int mi = 0; mi < 4; mi++) {
#pragma unroll
    for (int j = 0; j < 4; j++) {
      int rb = wr + mi*16 + (lane >> 4)*4 + j;
      if (rb < nrows) {
        int r = rl[rb];
        float s = tw[r];
        int col0 = n0 + wc + (lane & 15);
        if (MODE == 0) {
          float* dst = scrf + (size_t)r * NDIM + col0;
#pragma unroll
          for (int ni = 0; ni < 4; ni++) dst[ni*16] = acc[mi][ni][j] * s;
        } else if (MODE == 1) {
          bf16_t* dst = scrb + (size_t)r * NDIM + col0;
#pragma unroll
          for (int ni = 0; ni < 4; ni++) dst[ni*16] = (bf16_t)(acc[mi][ni][j] * s);
        } else {
          float* dst = outp + (size_t)(r >> 1) * NDIM + col0;
#pragma unroll
          for (int ni = 0; ni < 4; ni++) atomicAdd(dst + ni*16, acc[mi][ni][j] * s);
        }
      }
    }
  }
}

// ---------------- 5. pair reduce ----------------
__global__ void reduce_f32_kernel(const float* __restrict__ scr, float* __restrict__ out) {
  const int n4 = NTOK * NDIM / 4;   // float4 count
  int stride = gridDim.x * blockDim.x;
  for (int i = blockIdx.x * blockDim.x + threadIdx.x; i < n4; i += stride) {
    int tk = i >> 9;                // token (NDIM/4 = 512 float4 per row)
    int h  = i & 511;
    float4 a = ((const float4*)scr)[(size_t)tk*1024 + h];
    float4 b = ((const float4*)scr)[(size_t)tk*1024 + 512 + h];
    float4 o = {a.x+b.x, a.y+b.y, a.z+b.z, a.w+b.w};
    ((float4*)out)[i] = o;
  }
}
__global__ void reduce_bf16_kernel(const bf16_t* __restrict__ scr, float* __restrict__ out) {
  const int n4 = NTOK * NDIM / 4;
  int stride = gridDim.x * blockDim.x;
  for (int i = blockIdx.x * blockDim.x + threadIdx.x; i < n4; i += stride) {
    int tk = i >> 9;
    int h  = i & 511;
    bf16x4 a = ((const bf16x4*)scr)[(size_t)tk*1024 + h];
    bf16x4 b = ((const bf16x4*)scr)[(size_t)tk*1024 + 512 + h];
    float4 o = {(float)a[0] + (float)b[0], (float)a[1] + (float)b[1],
                (float)a[2] + (float)b[2], (float)a[3] + (float)b[3]};
    ((float4*)out)[i] = o;
  }
}

// ---------------- launch ----------------
extern "C" void kernel_launch(void* const* d_in, const int* in_sizes, int n_in,
                              void* d_out, int out_size, void* d_ws, size_t ws_size,
                              hipStream_t stream) {
  const float* x      = (const float*)d_in[0];
  const float* w      = (const float*)d_in[1];
  const float* logits = (const float*)d_in[2];
  float* out = (float*)d_out;

  char* ws = (char*)d_ws;
  float*  tw      = (float*)(ws + OFF_TW);
  int*    cnt     = (int*)  (ws + OFF_CNT);
  int4*   wl      = (int4*) (ws + OFF_WL);
  int*    rowlist = (int*)  (ws + OFF_RL);
  bf16_t* xb      = (bf16_t*)(ws + OFF_XB);
  bf16_t* wb      = (bf16_t*)(ws + OFF_WB);
  float*  scrf    = (float*) (ws + OFF_SCR);
  bf16_t* scrb    = (bf16_t*)(ws + OFF_SCR);

  hipMemsetAsync(cnt, 0, NEXP * sizeof(int), stream);
  routing_kernel<<<NTOK/256, 256, 0, stream>>>(logits, tw, cnt, rowlist);
  build_wl_kernel<<<1, 256, 0, stream>>>(cnt, wl);
  cvt_x_kernel<<<2048, 256, 0, stream>>>(x, xb);
  cvt_w_kernel<<<dim3(NDIM/64, KDIM/64, NEXP), 256, 0, stream>>>(w, wb);

  if (ws_size >= NEED_F32) {
    gemm_kernel<0><<<GRID_G, 256, 0, stream>>>(xb, wb, rowlist, wl, tw, scrf, nullptr, nullptr);
    reduce_f32_kernel<<<2048, 256, 0, stream>>>(scrf, out);
  } else if (ws_size >= NEED_BF16) {
    gemm_kernel<1><<<GRID_G, 256, 0, stream>>>(xb, wb, rowlist, wl, tw, nullptr, scrb, nullptr);
    reduce_bf16_kernel<<<2048, 256, 0, stream>>>(scrb, out);
  } else {
    hipMemsetAsync(d_out, 0, (size_t)NTOK * NDIM * sizeof(float), stream);
    gemm_kernel<2><<<GRID_G, 256, 0, stream>>>(xb, wb, rowlist, wl, tw, nullptr, nullptr, out);
  }
}

// Round 3
// 251.235 us; speedup vs baseline: 1.0198x; 1.0198x over previous
//
#include <hip/hip_runtime.h>
#include <hip/hip_bf16.h>

// ---------------- problem constants ----------------
#define NTOK   8192
#define TOPK   2
#define NROWS  (NTOK*TOPK)      // 16384
#define NEXP   8
#define KDIM   1024             // inner (INTER)
#define NDIM   2048             // output (HIDDEN)
#define TILE_M 256
#define MAX_T2 72               // sum ceil(cnt_e/256) <= 64+8
#define NT2    (NDIM/256)       // 8
#define GRID2  (MAX_T2*NT2)     // 576, divisible by 8

typedef __bf16 bf16_t;
typedef __bf16 bf16x8 __attribute__((ext_vector_type(8)));
typedef __bf16 bf16x4 __attribute__((ext_vector_type(4)));
typedef float  f32x4  __attribute__((ext_vector_type(4)));

static_assert(sizeof(bf16x8) == 16, "bf16x8 must be 16B");

// ---------------- ws layout (bytes) ----------------
#define OFF_TW    ((size_t)0)                    // 16384 f32 = 64KB
#define OFF_CNT   ((size_t)(1<<16))              // 8 i32
#define OFF_WL    ((size_t)((1<<16) + 1024))     // 72 * int4
#define OFF_RL    ((size_t)(1<<18))              // 8*16384 i32 = 512KB
#define OFF_XB    ((size_t)(1<<20))              // 16384*1024 bf16 = 32MB
#define OFF_WB    ((size_t)(34u<<20))            // 8*2048*1024 bf16 = 32MB
#define OFF_SCR   ((size_t)(68u<<20))            // scratch
#define NEED_BF16 (OFF_SCR + (size_t)NROWS*NDIM*2)   // ~132MB

#define VMCNT(n) asm volatile("s_waitcnt vmcnt(" #n ")" ::: "memory")

__device__ __forceinline__ void gload_lds16(const bf16_t* g, char* l) {
  __builtin_amdgcn_global_load_lds(
      (const __attribute__((address_space(1))) void*)g,
      (__attribute__((address_space(3))) void*)(void*)l, 16, 0, 0);
}

// ---------------- 1. routing: softmax + top2 + bucket (fused) ----------------
__global__ void routing_kernel(const float* __restrict__ logits,
                               float* __restrict__ tw,
                               int* __restrict__ cnt, int* __restrict__ rowlist) {
  int t = blockIdx.x * blockDim.x + threadIdx.x;
  if (t >= NTOK) return;
  float4 a = *(const float4*)(logits + (size_t)t*NEXP);
  float4 b = *(const float4*)(logits + (size_t)t*NEXP + 4);
  float l[8] = {a.x, a.y, a.z, a.w, b.x, b.y, b.z, b.w};
  float m = l[0];
#pragma unroll
  for (int i = 1; i < 8; i++) m = fmaxf(m, l[i]);
  float p[8], s = 0.f;
#pragma unroll
  for (int i = 0; i < 8; i++) { p[i] = __expf(l[i] - m); s += p[i]; }
  int e0 = 0; float b0 = p[0];
#pragma unroll
  for (int i = 1; i < 8; i++) if (p[i] > b0) { b0 = p[i]; e0 = i; }
  int e1 = (e0 == 0) ? 1 : 0; float b1 = p[e1];
#pragma unroll
  for (int i = 0; i < 8; i++) if (i != e0 && p[i] > b1) { b1 = p[i]; e1 = i; }
  float inv = 1.f / s;
  tw[2*t]   = b0 * inv;
  tw[2*t+1] = b1 * inv;
  int pos0 = atomicAdd(&cnt[e0], 1);
  rowlist[(size_t)e0*NROWS + pos0] = 2*t;
  int pos1 = atomicAdd(&cnt[e1], 1);
  rowlist[(size_t)e1*NROWS + pos1] = 2*t + 1;
}

// ---------------- 2. worklist of (expert,row-tile of 256) ----------------
__global__ void build_wl_kernel(const int* __restrict__ cnt, int4* __restrict__ wl) {
  __shared__ int base[NEXP+1];
  if (threadIdx.x == 0) {
    int acc = 0;
    for (int e = 0; e < NEXP; e++) { base[e] = acc; acc += (cnt[e] + 255) >> 8; }
    base[NEXP] = acc;
  }
  __syncthreads();
  int t = threadIdx.x;
  if (t < MAX_T2) {
    int4 v = {0, 0, 0, 0};
#pragma unroll
    for (int e = 0; e < NEXP; e++) {
      if (t >= base[e] && t < base[e+1]) {
        int rb = (t - base[e]) << 8;
        int c  = cnt[e];
        v.x = e; v.y = rb; v.z = (c - rb < 256) ? (c - rb) : 256;
      }
    }
    wl[t] = v;
  }
}

// ---------------- 3a. convert x -> bf16 ----------------
__global__ void cvt_x_kernel(const float* __restrict__ x, bf16_t* __restrict__ xb) {
  const int n8 = NROWS * KDIM / 8;
  int stride = gridDim.x * blockDim.x;
  for (int i = blockIdx.x * blockDim.x + threadIdx.x; i < n8; i += stride) {
    float4 v0 = ((const float4*)x)[2*(size_t)i];
    float4 v1 = ((const float4*)x)[2*(size_t)i + 1];
    bf16x8 o = { (bf16_t)v0.x, (bf16_t)v0.y, (bf16_t)v0.z, (bf16_t)v0.w,
                 (bf16_t)v1.x, (bf16_t)v1.y, (bf16_t)v1.z, (bf16_t)v1.w };
    *(bf16x8*)(xb + (size_t)i*8) = o;
  }
}

// ---------------- 3b. convert+transpose w -> bf16 [E][N][K] ----------------
// 64n x 64k per block; fp32 LDS [64][65] => conflict-free scalar writes/reads.
__global__ void cvt_w_kernel(const float* __restrict__ w, bf16_t* __restrict__ wb) {
  __shared__ float tf[64*65];
  int e  = blockIdx.z;
  int n0 = blockIdx.x * 64;
  int k0 = blockIdx.y * 64;
  int t  = threadIdx.x;
  const float* src = w + (size_t)e*KDIM*NDIM + (size_t)k0*NDIM + n0;
#pragma unroll
  for (int i = 0; i < 4; i++) {
    int idx = t + i*256;
    int kr  = idx >> 4;
    int nc4 = (idx & 15) * 4;
    float4 v = *(const float4*)(src + (size_t)kr*NDIM + nc4);
    tf[kr*65 + nc4+0] = v.x; tf[kr*65 + nc4+1] = v.y;
    tf[kr*65 + nc4+2] = v.z; tf[kr*65 + nc4+3] = v.w;
  }
  __syncthreads();
  bf16_t* dst = wb + (size_t)e*NDIM*KDIM + (size_t)n0*KDIM + k0;
#pragma unroll
  for (int i = 0; i < 2; i++) {
    int idx = t + i*256;
    int nr  = idx >> 3;
    int kc  = (idx & 7) * 8;
    bf16x8 o;
#pragma unroll
    for (int j = 0; j < 8; j++) o[j] = (bf16_t)tf[(kc+j)*65 + nr];
    *(bf16x8*)(dst + (size_t)nr*KDIM + kc) = o;
  }
}

// ---------------- 4. grouped GEMM: 256x256 tile, BK=64, 8-phase schedule ------
// 8 waves (2M x 4N), per-wave 128x64 out. LDS 128KB: A/B x dbuf x [2half][128][64]
// slot-swizzle: physical 16B slot p of row R holds logical slot p ^ (R&7).
// Counted vmcnt(6) at phases 4/8 only (T4); setprio around MFMA (T5).
// MODE 1: bf16 scratch   MODE 2: atomic into out
#define AC(buf,h,j) ((buf)*32768 + (h)*16384 + (j)*8192)
#define BC(buf,h,j) (65536 + (buf)*32768 + (h)*16384 + (j)*8192)
#define STG(gp, c)  gload_lds16((gp), smemw + (c))

#define PHASE(q, buf, STAGES) do {                                             \
    bf16x8 aw[2][2];                                                           \
    _Pragma("unroll") for (int m2 = 0; m2 < 2; ++m2)                           \
      _Pragma("unroll") for (int kk = 0; kk < 2; ++kk)                         \
        aw[m2][kk] = *(const bf16x8*)(baseA[buf][kk] + ((q)*2 + m2) * 2048);   \
    if ((q) == 0) {                                                            \
      _Pragma("unroll") for (int n = 0; n < 4; ++n)                            \
        _Pragma("unroll") for (int kk = 0; kk < 2; ++kk)                       \
          bfrag[n][kk] = *(const bf16x8*)(baseB[buf][kk] + n * 2048);          \
    }                                                                          \
    STAGES;                                                                    \
    __builtin_amdgcn_s_barrier();                                              \
    __builtin_amdgcn_s_setprio(1);                                             \
    _Pragma("unroll") for (int m2 = 0; m2 < 2; ++m2)                           \
      _Pragma("unroll") for (int n = 0; n < 4; ++n)                            \
        _Pragma("unroll") for (int kk = 0; kk < 2; ++kk)                       \
          acc[(q)*2+m2][n] = __builtin_amdgcn_mfma_f32_16x16x32_bf16(          \
              aw[m2][kk], bfrag[n][kk], acc[(q)*2+m2][n], 0, 0, 0);            \
    __builtin_amdgcn_s_setprio(0);                                             \
    __builtin_amdgcn_s_barrier();                                              \
  } while (0)

template <int MODE>
__global__ __launch_bounds__(512, 2)
void gemm256_kernel(const bf16_t* __restrict__ xb,     // [NROWS][KDIM]
                    const bf16_t* __restrict__ wb,     // [NEXP][NDIM][KDIM]
                    const int*    __restrict__ rowlist,
                    const int4*   __restrict__ wl,
                    const float*  __restrict__ tw,
                    bf16_t*       __restrict__ scrb,
                    float*        __restrict__ outp) {
  extern __shared__ char smem[];   // 131072 B

  // XCD-bijective swizzle: 576 = 8 * 72
  int bid = blockIdx.x;
  int lin = (bid & 7) * (GRID2/8) + (bid >> 3);
  int yt  = lin >> 3;              // row-tile 0..71
  int xt  = lin & 7;               // n-tile 0..7

  int4 wle = wl[yt];
  const int nrows = wle.z;
  if (nrows <= 0) return;
  const int e  = wle.x;
  const int n0 = xt * 256;

  const int t    = threadIdx.x;
  const int lane = t & 63;
  const int wv   = t >> 6;         // 0..7
  const int wm   = wv >> 2;        // 0..1 (M)
  const int wn   = wv & 3;         // 0..3 (N)

  // ---- staging addressing (inverse-swizzled global source, rule 21) ----
  const int srow  = (wv << 3) + (lane >> 3);         // 0..63
  const int pslot = lane & 7;
  const int lslot = pslot ^ ((lane >> 3) & 7);       // logical 16B slot
  const int kof   = lslot * 8;                        // k-elem offset within 64

  const int* rl = rowlist + (size_t)e*NROWS + wle.y;
  const bf16_t *pA00, *pA01, *pA10, *pA11, *pB00, *pB01, *pB10, *pB11;
  {
    const bf16_t* wbase = wb + (size_t)e*NDIM*KDIM;
    int t00 = 0*128 + 0*64 + srow, t01 = 0*128 + 1*64 + srow;
    int t10 = 1*128 + 0*64 + srow, t11 = 1*128 + 1*64 + srow;
    int r00 = rl[t00 < nrows ? t00 : nrows-1];
    int r01 = rl[t01 < nrows ? t01 : nrows-1];
    int r10 = rl[t10 < nrows ? t10 : nrows-1];
    int r11 = rl[t11 < nrows ? t11 : nrows-1];
    pA00 = xb + (size_t)r00*KDIM + kof;  pA01 = xb + (size_t)r01*KDIM + kof;
    pA10 = xb + (size_t)r10*KDIM + kof;  pA11 = xb + (size_t)r11*KDIM + kof;
    pB00 = wbase + (size_t)(n0 + t00)*KDIM + kof;
    pB01 = wbase + (size_t)(n0 + t01)*KDIM + kof;
    pB10 = wbase + (size_t)(n0 + t10)*KDIM + kof;
    pB11 = wbase + (size_t)(n0 + t11)*KDIM + kof;
  }
  char* smemw = smem + (wv << 10);   // wave's 1KB staging chunk base

  // ---- ds_read fragment bases (swizzled read side) ----
  const int lr = lane & 15;
  const int l4 = lane >> 4;                         // 0..3
  const int colA0 = ((l4 ^ (lr & 7)) << 4);         // kk=0 byte col
  const char* baseA[2][2];
  const char* baseB[2][2];
#pragma unroll
  for (int b = 0; b < 2; b++)
#pragma unroll
    for (int kk = 0; kk < 2; kk++) {
      int col = colA0 ^ (kk << 6);
      baseA[b][kk] = smem + b*32768 + wm*16384 + lr*128 + col;
      baseB[b][kk] = smem + 65536 + b*32768 + (wn>>1)*16384 + ((wn&1)*64 + lr)*128 + col;
    }

  f32x4  acc[8][4] = {};
  bf16x8 bfrag[4][2];

  // ---- prologue: tile0 complete (8 units) + tile1 B(4) + A(h,0)(2) ----
  STG(pA00, AC(0,0,0)); STG(pA01, AC(0,0,1)); STG(pA10, AC(0,1,0)); STG(pA11, AC(0,1,1));
  STG(pB00, BC(0,0,0)); STG(pB01, BC(0,0,1)); STG(pB10, BC(0,1,0)); STG(pB11, BC(0,1,1));
  STG(pB00+64, BC(1,0,0)); STG(pB01+64, BC(1,0,1));
  STG(pB10+64, BC(1,1,0)); STG(pB11+64, BC(1,1,1));
  STG(pA00+64, AC(1,0,0)); STG(pA10+64, AC(1,1,0));
  pA00 += 128; pA01 += 128; pA10 += 128; pA11 += 128;
  pB00 += 128; pB01 += 128; pB10 += 128; pB11 += 128;
  VMCNT(6);                        // tile0 landed; tile1's 6 may fly
  __builtin_amdgcn_s_barrier();

  // ---- main loop: 8 iterations x 2 K-tiles (K=1024, BK=64) ----
  for (int i = 0; i < 8; ++i) {
    const bool st = (i < 7);
    // tiles: cur even->buf0 (ph1-4), odd->buf1 (ph5-8); stage tiles +2,+3
    PHASE(0, 0, { STG(pA01 - 64, AC(1,0,1)); STG(pA11 - 64, AC(1,1,1)); });
    PHASE(1, 0, { if (st) { STG(pB00, BC(0,0,0)); STG(pB01, BC(0,0,1)); } });
    PHASE(2, 0, { if (st) { STG(pB10, BC(0,1,0)); STG(pB11, BC(0,1,1)); } });
    PHASE(3, 0, { if (st) { STG(pA00, AC(0,0,0)); STG(pA10, AC(0,1,0)); VMCNT(6); }
                  else VMCNT(0); });
    PHASE(0, 1, { if (st) { STG(pA01, AC(0,0,1)); STG(pA11, AC(0,1,1)); } });
    PHASE(1, 1, { if (st) { STG(pB00+64, BC(1,0,0)); STG(pB01+64, BC(1,0,1)); } });
    PHASE(2, 1, { if (st) { STG(pB10+64, BC(1,1,0)); STG(pB11+64, BC(1,1,1)); } });
    PHASE(3, 1, { if (st) { STG(pA00+64, AC(1,0,0)); STG(pA10+64, AC(1,1,0)); VMCNT(6); } });
    pA00 += 128; pA01 += 128; pA10 += 128; pA11 += 128;
    pB00 += 128; pB01 += 128; pB10 += 128; pB11 += 128;
  }

  // ---- epilogue: C/D layout col = lane&15, row = l4*4 + jj ----
#pragma unroll
  for (int mf = 0; mf < 8; mf++) {
#pragma unroll
    for (int jj = 0; jj < 4; jj++) {
      int rb = wm*128 + mf*16 + l4*4 + jj;
      if (rb < nrows) {
        int r = rl[rb];
        float s = tw[r];
        int col0 = n0 + wn*64 + (lane & 15);
        if (MODE == 1) {
          bf16_t* dst = scrb + (size_t)r*NDIM + col0;
#pragma unroll
          for (int n = 0; n < 4; n++) dst[n*16] = (bf16_t)(acc[mf][n][jj] * s);
        } else {
          float* dst = outp + (size_t)(r >> 1)*NDIM + col0;
#pragma unroll
          for (int n = 0; n < 4; n++) atomicAdd(dst + n*16, acc[mf][n][jj] * s);
        }
      }
    }
  }
}

// ---------------- 5. pair reduce (bf16 scratch -> fp32 out) ----------------
__global__ void reduce_bf16_kernel(const bf16_t* __restrict__ scr, float* __restrict__ out) {
  const int n4 = NTOK * NDIM / 4;
  int stride = gridDim.x * blockDim.x;
  for (int i = blockIdx.x * blockDim.x + threadIdx.x; i < n4; i += stride) {
    int tk = i >> 9;
    int h  = i & 511;
    bf16x4 a = ((const bf16x4*)scr)[(size_t)tk*1024 + h];
    bf16x4 b = ((const bf16x4*)scr)[(size_t)tk*1024 + 512 + h];
    float4 o = {(float)a[0] + (float)b[0], (float)a[1] + (float)b[1],
                (float)a[2] + (float)b[2], (float)a[3] + (float)b[3]};
    ((float4*)out)[i] = o;
  }
}

// ---------------- launch ----------------
extern "C" void kernel_launch(void* const* d_in, const int* in_sizes, int n_in,
                              void* d_out, int out_size, void* d_ws, size_t ws_size,
                              hipStream_t stream) {
  const float* x      = (const float*)d_in[0];
  const float* w      = (const float*)d_in[1];
  const float* logits = (const float*)d_in[2];
  float* out = (float*)d_out;

  char* ws = (char*)d_ws;
  float*  tw      = (float*)(ws + OFF_TW);
  int*    cnt     = (int*)  (ws + OFF_CNT);
  int4*   wl      = (int4*) (ws + OFF_WL);
  int*    rowlist = (int*)  (ws + OFF_RL);
  bf16_t* xb      = (bf16_t*)(ws + OFF_XB);
  bf16_t* wb      = (bf16_t*)(ws + OFF_WB);
  bf16_t* scrb    = (bf16_t*)(ws + OFF_SCR);

  hipMemsetAsync(cnt, 0, NEXP * sizeof(int), stream);
  routing_kernel<<<NTOK/256, 256, 0, stream>>>(logits, tw, cnt, rowlist);
  build_wl_kernel<<<1, 128, 0, stream>>>(cnt, wl);
  cvt_x_kernel<<<2048, 256, 0, stream>>>(x, xb);
  cvt_w_kernel<<<dim3(NDIM/64, KDIM/64, NEXP), 256, 0, stream>>>(w, wb);

  if (ws_size >= NEED_BF16) {
    gemm256_kernel<1><<<GRID2, 512, 131072, stream>>>(xb, wb, rowlist, wl, tw, scrb, nullptr);
    reduce_bf16_kernel<<<2048, 256, 0, stream>>>(scrb, out);
  } else {
    hipMemsetAsync(d_out, 0, (size_t)NTOK * NDIM * sizeof(float), stream);
    gemm256_kernel<2><<<GRID2, 512, 131072, stream>>>(xb, wb, rowlist, wl, tw, nullptr, out);
  }
}

// Round 4
// 250.860 us; speedup vs baseline: 1.0213x; 1.0015x over previous
//
#include <hip/hip_runtime.h>
#include <hip/hip_bf16.h>

// ---------------- problem constants ----------------
#define NTOK   8192
#define TOPK   2
#define NROWS  (NTOK*TOPK)      // 16384
#define NEXP   8
#define KDIM   1024             // inner (INTER)
#define NDIM   2048             // output (HIDDEN)
#define MAX_T2 72               // sum ceil(cnt_e/256) <= 64+8
#define NT2    (NDIM/256)       // 8
#define GRID2  (MAX_T2*NT2)     // 576, divisible by 8

typedef __bf16 bf16_t;
typedef __bf16 bf16x8 __attribute__((ext_vector_type(8)));
typedef __bf16 bf16x4 __attribute__((ext_vector_type(4)));
typedef float  f32x4  __attribute__((ext_vector_type(4)));

static_assert(sizeof(bf16x8) == 16, "bf16x8 must be 16B");

// ---------------- ws layout (bytes) ----------------
#define OFF_TW    ((size_t)0)                    // 16384 f32 = 64KB
#define OFF_CNT   ((size_t)(1<<16))              // 8 i32
#define OFF_WL    ((size_t)((1<<16) + 1024))     // 72 * int4
#define OFF_RL    ((size_t)(1<<18))              // 8*16384 i32 = 512KB
#define OFF_XB    ((size_t)(1<<20))              // 16384*1024 bf16 = 32MB
#define OFF_WB    ((size_t)(34u<<20))            // 8*2048*1024 bf16 = 32MB
#define OFF_SCR   ((size_t)(68u<<20))            // scratch
#define NEED_BF16 (OFF_SCR + (size_t)NROWS*NDIM*2)   // ~132MB

#define VMCNT(n) asm volatile("s_waitcnt vmcnt(" #n ")" ::: "memory")

__device__ __forceinline__ void gload_lds16(const bf16_t* g, const char* l) {
  __builtin_amdgcn_global_load_lds(
      (const __attribute__((address_space(1))) void*)g,
      (__attribute__((address_space(3))) void*)(void*)l, 16, 0, 0);
}

// ---------------- 1. routing: softmax + top2 + bucket (fused) ----------------
__global__ void routing_kernel(const float* __restrict__ logits,
                               float* __restrict__ tw,
                               int* __restrict__ cnt, int* __restrict__ rowlist) {
  int t = blockIdx.x * blockDim.x + threadIdx.x;
  if (t >= NTOK) return;
  float4 a = *(const float4*)(logits + (size_t)t*NEXP);
  float4 b = *(const float4*)(logits + (size_t)t*NEXP + 4);
  float l[8] = {a.x, a.y, a.z, a.w, b.x, b.y, b.z, b.w};
  float m = l[0];
#pragma unroll
  for (int i = 1; i < 8; i++) m = fmaxf(m, l[i]);
  float p[8], s = 0.f;
#pragma unroll
  for (int i = 0; i < 8; i++) { p[i] = __expf(l[i] - m); s += p[i]; }
  int e0 = 0; float b0 = p[0];
#pragma unroll
  for (int i = 1; i < 8; i++) if (p[i] > b0) { b0 = p[i]; e0 = i; }
  int e1 = (e0 == 0) ? 1 : 0; float b1 = p[e1];
#pragma unroll
  for (int i = 0; i < 8; i++) if (i != e0 && p[i] > b1) { b1 = p[i]; e1 = i; }
  float inv = 1.f / s;
  tw[2*t]   = b0 * inv;
  tw[2*t+1] = b1 * inv;
  int pos0 = atomicAdd(&cnt[e0], 1);
  rowlist[(size_t)e0*NROWS + pos0] = 2*t;
  int pos1 = atomicAdd(&cnt[e1], 1);
  rowlist[(size_t)e1*NROWS + pos1] = 2*t + 1;
}

// ---------------- 2. worklist of (expert,row-tile of 256) ----------------
__global__ void build_wl_kernel(const int* __restrict__ cnt, int4* __restrict__ wl) {
  __shared__ int base[NEXP+1];
  if (threadIdx.x == 0) {
    int acc = 0;
    for (int e = 0; e < NEXP; e++) { base[e] = acc; acc += (cnt[e] + 255) >> 8; }
    base[NEXP] = acc;
  }
  __syncthreads();
  int t = threadIdx.x;
  if (t < MAX_T2) {
    int4 v = {0, 0, 0, 0};
#pragma unroll
    for (int e = 0; e < NEXP; e++) {
      if (t >= base[e] && t < base[e+1]) {
        int rb = (t - base[e]) << 8;
        int c  = cnt[e];
        v.x = e; v.y = rb; v.z = (c - rb < 256) ? (c - rb) : 256;
      }
    }
    wl[t] = v;
  }
}

// ---------------- 3a. convert x -> bf16 ----------------
__global__ void cvt_x_kernel(const float* __restrict__ x, bf16_t* __restrict__ xb) {
  int i = blockIdx.x * blockDim.x + threadIdx.x;   // one bf16x8 per thread
  float4 v0 = ((const float4*)x)[2*(size_t)i];
  float4 v1 = ((const float4*)x)[2*(size_t)i + 1];
  bf16x8 o = { (bf16_t)v0.x, (bf16_t)v0.y, (bf16_t)v0.z, (bf16_t)v0.w,
               (bf16_t)v1.x, (bf16_t)v1.y, (bf16_t)v1.z, (bf16_t)v1.w };
  *(bf16x8*)(xb + (size_t)i*8) = o;
}

// ---------------- 3b. convert+transpose w -> bf16 [E][N][K] ----------------
__global__ void cvt_w_kernel(const float* __restrict__ w, bf16_t* __restrict__ wb) {
  __shared__ float tf[64*65];
  int e  = blockIdx.z;
  int n0 = blockIdx.x * 64;
  int k0 = blockIdx.y * 64;
  int t  = threadIdx.x;
  const float* src = w + (size_t)e*KDIM*NDIM + (size_t)k0*NDIM + n0;
#pragma unroll
  for (int i = 0; i < 4; i++) {
    int idx = t + i*256;
    int kr  = idx >> 4;
    int nc4 = (idx & 15) * 4;
    float4 v = *(const float4*)(src + (size_t)kr*NDIM + nc4);
    tf[kr*65 + nc4+0] = v.x; tf[kr*65 + nc4+1] = v.y;
    tf[kr*65 + nc4+2] = v.z; tf[kr*65 + nc4+3] = v.w;
  }
  __syncthreads();
  bf16_t* dst = wb + (size_t)e*NDIM*KDIM + (size_t)n0*KDIM + k0;
#pragma unroll
  for (int i = 0; i < 2; i++) {
    int idx = t + i*256;
    int nr  = idx >> 3;
    int kc  = (idx & 7) * 8;
    bf16x8 o;
#pragma unroll
    for (int j = 0; j < 8; j++) o[j] = (bf16_t)tf[(kc+j)*65 + nr];
    *(bf16x8*)(dst + (size_t)nr*KDIM + kc) = o;
  }
}

// ---------------- 4. grouped GEMM: 256x256, BK=64, 8-phase, hardened ---------
// LDS 128KB: A = 2buf x [2h][2j][64rows][8slots of 16B], B same at +65536.
// slot swizzle: physical slot p of row R holds logical slot p ^ (R&7).
// All fragment reads: ds_read_b128 from &smem[int_base + imm].
#define AC(buf,h,j) ((buf)*32768 + (h)*16384 + (j)*8192)
#define BC(buf,h,j) (65536 + (buf)*32768 + (h)*16384 + (j)*8192)
#define STG(gp, c)  gload_lds16((gp), &smem[(c) + smemwo])
#define LDSA(buf,f,kk)  (*(const bf16x8*)&smem[((kk) ? bAx : bA) + (buf)*32768 + (f)*2048])
#define LDSB(buf,nf,kk) (*(const bf16x8*)&smem[((kk) ? bBx : bB) + (buf)*32768 + (nf)*2048])

#define PH(q, buf, ...) do {                                                   \
    bf16x8 a0 = LDSA(buf, (q)*2+0, 0), a0x = LDSA(buf, (q)*2+0, 1);            \
    bf16x8 a1 = LDSA(buf, (q)*2+1, 0), a1x = LDSA(buf, (q)*2+1, 1);            \
    if ((q) == 0) {                                                            \
      _Pragma("unroll") for (int nf = 0; nf < 4; ++nf) {                       \
        bfrag[nf][0] = LDSB(buf, nf, 0); bfrag[nf][1] = LDSB(buf, nf, 1); }    \
    }                                                                          \
    __VA_ARGS__;                                                               \
    __builtin_amdgcn_s_barrier();                                              \
    __builtin_amdgcn_s_setprio(1);                                             \
    _Pragma("unroll") for (int nf = 0; nf < 4; ++nf) {                         \
      acc[(q)*2+0][nf] = __builtin_amdgcn_mfma_f32_16x16x32_bf16(a0,  bfrag[nf][0], acc[(q)*2+0][nf], 0,0,0); \
      acc[(q)*2+0][nf] = __builtin_amdgcn_mfma_f32_16x16x32_bf16(a0x, bfrag[nf][1], acc[(q)*2+0][nf], 0,0,0); \
      acc[(q)*2+1][nf] = __builtin_amdgcn_mfma_f32_16x16x32_bf16(a1,  bfrag[nf][0], acc[(q)*2+1][nf], 0,0,0); \
      acc[(q)*2+1][nf] = __builtin_amdgcn_mfma_f32_16x16x32_bf16(a1x, bfrag[nf][1], acc[(q)*2+1][nf], 0,0,0); \
    }                                                                          \
    __builtin_amdgcn_s_setprio(0);                                             \
    __builtin_amdgcn_s_barrier();                                              \
  } while (0)

template <int MODE>
__global__ __launch_bounds__(512, 2)
void gemm256_kernel(const bf16_t* __restrict__ xb,     // [NROWS][KDIM]
                    const bf16_t* __restrict__ wb,     // [NEXP][NDIM][KDIM]
                    const int*    __restrict__ rowlist,
                    const int4*   __restrict__ wl,
                    const float*  __restrict__ tw,
                    bf16_t*       __restrict__ scrb,
                    float*        __restrict__ outp) {
  extern __shared__ char smem[];   // 131072 B

  int bid = blockIdx.x;
  int lin = (bid & 7) * (GRID2/8) + (bid >> 3);
  int yt  = lin >> 3;
  int xt  = lin & 7;

  int4 wle = wl[yt];
  const int nrows = wle.z;
  if (nrows <= 0) return;
  const int e  = wle.x;
  const int n0 = xt * 256;

  const int t    = threadIdx.x;
  const int lane = t & 63;
  const int wv   = t >> 6;         // 0..7
  const int wm   = wv >> 2;        // 0..1
  const int wn   = wv & 3;         // 0..3

  // ---- staging addressing (linear LDS dest, inverse-swizzled global src) ----
  const int srow   = (wv << 3) + (lane >> 3);        // 0..63 within unit
  const int pslot  = lane & 7;
  const int kof    = (pslot ^ (srow & 7)) * 8;       // logical k-elem offset
  const int smemwo = wv << 10;                       // wave's 1KB chunk in unit

  const int* rl = rowlist + (size_t)e*NROWS + wle.y;
  const bf16_t *pA00, *pA01, *pA10, *pA11, *pB00, *pB01, *pB10, *pB11;
  {
    const bf16_t* wbase = wb + (size_t)e*NDIM*KDIM;
    int t00 = 0*128 + 0*64 + srow, t01 = 0*128 + 1*64 + srow;
    int t10 = 1*128 + 0*64 + srow, t11 = 1*128 + 1*64 + srow;
    int r00 = rl[t00 < nrows ? t00 : nrows-1];
    int r01 = rl[t01 < nrows ? t01 : nrows-1];
    int r10 = rl[t10 < nrows ? t10 : nrows-1];
    int r11 = rl[t11 < nrows ? t11 : nrows-1];
    pA00 = xb + (size_t)r00*KDIM + kof;  pA01 = xb + (size_t)r01*KDIM + kof;
    pA10 = xb + (size_t)r10*KDIM + kof;  pA11 = xb + (size_t)r11*KDIM + kof;
    pB00 = wbase + (size_t)(n0 + t00)*KDIM + kof;
    pB01 = wbase + (size_t)(n0 + t01)*KDIM + kof;
    pB10 = wbase + (size_t)(n0 + t10)*KDIM + kof;
    pB11 = wbase + (size_t)(n0 + t11)*KDIM + kof;
  }

  // ---- fragment read bases (int LDS byte offsets, swizzled) ----
  const int lr = lane & 15;
  const int l4 = lane >> 4;
  const int colsw = ((l4 ^ (lr & 7)) << 4);          // bits 4..6
  const int bA  = wm*16384 + lr*128 + colsw;
  const int bAx = bA ^ 64;
  const int bB  = 65536 + (wn>>1)*16384 + (wn&1)*8192 + lr*128 + colsw;
  const int bBx = bB ^ 64;

  f32x4  acc[8][4] = {};
  bf16x8 bfrag[4][2];

  // ---- prologue: tile0 complete (8) + tile1 B(4) + tile1 A-j0 (2) ----
  STG(pA00, AC(0,0,0)); STG(pA01, AC(0,0,1)); STG(pA10, AC(0,1,0)); STG(pA11, AC(0,1,1));
  STG(pB00, BC(0,0,0)); STG(pB01, BC(0,0,1)); STG(pB10, BC(0,1,0)); STG(pB11, BC(0,1,1));
  STG(pB00+64, BC(1,0,0)); STG(pB01+64, BC(1,0,1));
  STG(pB10+64, BC(1,1,0)); STG(pB11+64, BC(1,1,1));
  STG(pA00+64, AC(1,0,0)); STG(pA10+64, AC(1,1,0));
  pA00 += 128; pA01 += 128; pA10 += 128; pA11 += 128;   // -> tile2
  pB00 += 128; pB01 += 128; pB10 += 128; pB11 += 128;
  VMCNT(6);                        // tile0 landed; tile1's 6 still in flight
  __builtin_amdgcn_s_barrier();

  // ---- main loop: iterations 0..6 compute tiles 2i,2i+1; stage 2i+2,2i+3 ----
#pragma unroll 1
  for (int i = 0; i < 7; ++i) {
    PH(0, 0, STG(pA01-64, AC(1,0,1)); STG(pA11-64, AC(1,1,1)) );   // t2i+1 A-j1
    PH(1, 0, STG(pB00,    BC(0,0,0)); STG(pB01,    BC(0,0,1)) );   // t2i+2 B h0
    PH(2, 0, STG(pB10,    BC(0,1,0)); STG(pB11,    BC(0,1,1)) );   // t2i+2 B h1
    PH(3, 0, STG(pA00,    AC(0,0,0)); STG(pA10,    AC(0,1,0)); VMCNT(6) ); // t2i+2 A-j0
    PH(0, 1, STG(pA01,    AC(0,0,1)); STG(pA11,    AC(0,1,1)) );   // t2i+2 A-j1
    PH(1, 1, STG(pB00+64, BC(1,0,0)); STG(pB01+64, BC(1,0,1)) );   // t2i+3 B h0
    PH(2, 1, STG(pB10+64, BC(1,1,0)); STG(pB11+64, BC(1,1,1)) );   // t2i+3 B h1
    PH(3, 1, STG(pA00+64, AC(1,0,0)); STG(pA10+64, AC(1,1,0)); VMCNT(6) ); // t2i+3 A-j0
    pA00 += 128; pA01 += 128; pA10 += 128; pA11 += 128;
    pB00 += 128; pB01 += 128; pB10 += 128; pB11 += 128;
  }

  // ---- drain iteration: tiles 14 (buf0), 15 (buf1) ----
  PH(0, 0, STG(pA01-64, AC(1,0,1)); STG(pA11-64, AC(1,1,1)) );     // t15 A-j1
  PH(1, 0, );
  PH(2, 0, );
  PH(3, 0, VMCNT(0) );
  PH(0, 1, );
  PH(1, 1, );
  PH(2, 1, );
  PH(3, 1, );

  // ---- epilogue: C/D col = lane&15, row = l4*4 + jj ----
#pragma unroll
  for (int mf = 0; mf < 8; mf++) {
#pragma unroll
    for (int jj = 0; jj < 4; jj++) {
      int rb = wm*128 + mf*16 + l4*4 + jj;
      if (rb < nrows) {
        int r = rl[rb];
        float s = tw[r];
        int col0 = n0 + wn*64 + lr;
        if (MODE == 1) {
          bf16_t* dst = scrb + (size_t)r*NDIM + col0;
#pragma unroll
          for (int n = 0; n < 4; n++) dst[n*16] = (bf16_t)(acc[mf][n][jj] * s);
        } else {
          float* dst = outp + (size_t)(r >> 1)*NDIM + col0;
#pragma unroll
          for (int n = 0; n < 4; n++) atomicAdd(dst + n*16, acc[mf][n][jj] * s);
        }
      }
    }
  }
}

// ---------------- 5. pair reduce (bf16 scratch -> fp32 out) ----------------
__global__ void reduce_bf16_kernel(const bf16_t* __restrict__ scr, float* __restrict__ out) {
  const int n4 = NTOK * NDIM / 4;
  int stride = gridDim.x * blockDim.x;
  for (int i = blockIdx.x * blockDim.x + threadIdx.x; i < n4; i += stride) {
    int tk = i >> 9;
    int h  = i & 511;
    bf16x4 a = ((const bf16x4*)scr)[(size_t)tk*1024 + h];
    bf16x4 b = ((const bf16x4*)scr)[(size_t)tk*1024 + 512 + h];
    float4 o = {(float)a[0] + (float)b[0], (float)a[1] + (float)b[1],
                (float)a[2] + (float)b[2], (float)a[3] + (float)b[3]};
    ((float4*)out)[i] = o;
  }
}

// ---------------- launch ----------------
extern "C" void kernel_launch(void* const* d_in, const int* in_sizes, int n_in,
                              void* d_out, int out_size, void* d_ws, size_t ws_size,
                              hipStream_t stream) {
  const float* x      = (const float*)d_in[0];
  const float* w      = (const float*)d_in[1];
  const float* logits = (const float*)d_in[2];
  float* out = (float*)d_out;

  char* ws = (char*)d_ws;
  float*  tw      = (float*)(ws + OFF_TW);
  int*    cnt     = (int*)  (ws + OFF_CNT);
  int4*   wl      = (int4*) (ws + OFF_WL);
  int*    rowlist = (int*)  (ws + OFF_RL);
  bf16_t* xb      = (bf16_t*)(ws + OFF_XB);
  bf16_t* wb      = (bf16_t*)(ws + OFF_WB);
  bf16_t* scrb    = (bf16_t*)(ws + OFF_SCR);

  hipMemsetAsync(cnt, 0, NEXP * sizeof(int), stream);
  routing_kernel<<<NTOK/256, 256, 0, stream>>>(logits, tw, cnt, rowlist);
  build_wl_kernel<<<1, 128, 0, stream>>>(cnt, wl);
  cvt_x_kernel<<<NROWS*KDIM/8/256, 256, 0, stream>>>(x, xb);
  cvt_w_kernel<<<dim3(NDIM/64, KDIM/64, NEXP), 256, 0, stream>>>(w, wb);

  if (ws_size >= NEED_BF16) {
    gemm256_kernel<1><<<GRID2, 512, 131072, stream>>>(xb, wb, rowlist, wl, tw, scrb, nullptr);
    reduce_bf16_kernel<<<2048, 256, 0, stream>>>(scrb, out);
  } else {
    hipMemsetAsync(d_out, 0, (size_t)NTOK * NDIM * sizeof(float), stream);
    gemm256_kernel<2><<<GRID2, 512, 131072, stream>>>(xb, wb, rowlist, wl, tw, nullptr, out);
  }
}